// Round 5
// baseline (253.674 us; speedup 1.0000x reference)
//
#include <hip/hip_runtime.h>
#include <math.h>

constexpr int HD   = 512;    // hidden
constexpr int LL   = 1024;   // SES*SEQ
constexpr int MT   = 16384;  // B*L rows
constexpr int KNBR = 32;     // K neighbors
constexpr float SCL = 0.04419417382415922f;  // 1/sqrt(512)

typedef __attribute__((ext_vector_type(8))) short  bf16x8;  // 8 bf16 = 4 VGPRs
typedef __attribute__((ext_vector_type(4))) float  f32x4;

__device__ inline float b2f(unsigned short u) {
    union { unsigned int i; float f; } v; v.i = (unsigned int)u << 16; return v.f;
}
__device__ inline float b2f_lo(unsigned int u) {
    union { unsigned int i; float f; } v; v.i = u << 16; return v.f;
}
__device__ inline float b2f_hi(unsigned int u) {
    union { unsigned int i; float f; } v; v.i = u & 0xffff0000u; return v.f;
}
__device__ inline unsigned short f2b(float x) {
    union { float f; unsigned int u; } v; v.f = x;
    unsigned int r = v.u + 0x7fff + ((v.u >> 16) & 1);
    return (unsigned short)(r >> 16);
}

// ================= prep: convs + q-proj + scores-init, one launch ==========
// blocks [0,8192):      item fp32->bf16 (1024 elems/block)
// blocks [8192,8960):   Wk,Wv,Wd fp32->bf16
// blocks [8960,11008):  q = user_emb @ Wq^T + bq (4 waves = 4 (b,h) outputs)
// blocks [11008,11024): scores[b,:] = SCL * dot(q[b], bk) (from user_emb)
constexpr int PB_CONV_I = 8192;
constexpr int PB_CONV_W = 768;
constexpr int PB_Q      = 2048;
constexpr int PB_SINIT  = 16;

__global__ __launch_bounds__(256) void prep(
    const float* __restrict__ item, const float* __restrict__ Wk,
    const float* __restrict__ Wv, const float* __restrict__ Wd,
    const float* __restrict__ u, const float* __restrict__ Wq,
    const float* __restrict__ bq, const float* __restrict__ bk,
    unsigned short* __restrict__ item_bf, unsigned short* __restrict__ Wkv_bf,
    unsigned short* __restrict__ Wd_bf, float* __restrict__ q,
    float* __restrict__ scores)
{
    const int blk = blockIdx.x, tid = threadIdx.x;

    if (blk < PB_CONV_I) {
        const int i = blk * 1024 + tid * 4;
        float4 v = *(const float4*)&item[i];
        ushort4 o;
        o.x = f2b(v.x); o.y = f2b(v.y); o.z = f2b(v.z); o.w = f2b(v.w);
        *(ushort4*)&item_bf[i] = o;
        return;
    }
    if (blk < PB_CONV_I + PB_CONV_W) {
        const int n = HD*HD;
        const int i = (blk - PB_CONV_I) * 1024 + tid * 4;
        const float* s; unsigned short* d; int off;
        if (i < n)        { s = Wk; d = Wkv_bf;     off = i; }
        else if (i < 2*n) { s = Wv; d = Wkv_bf + n; off = i - n; }
        else              { s = Wd; d = Wd_bf;      off = i - 2*n; }
        float4 v = *(const float4*)&s[off];
        ushort4 o;
        o.x = f2b(v.x); o.y = f2b(v.y); o.z = f2b(v.z); o.w = f2b(v.w);
        *(ushort4*)&d[off] = o;
        return;
    }
    if (blk < PB_CONV_I + PB_CONV_W + PB_Q) {
        const int wid  = (blk - PB_CONV_I - PB_CONV_W) * 4 + (tid >> 6);
        const int lane = tid & 63;
        const int b = wid >> 9, h = wid & 511;
        const float* ur = &u[b*HD + lane*8];
        const float* wr = &Wq[(size_t)h*HD + lane*8];
        const float4 u0 = *(const float4*)ur, u1 = *(const float4*)(ur+4);
        const float4 w0 = *(const float4*)wr, w1 = *(const float4*)(wr+4);
        float acc = u0.x*w0.x + u0.y*w0.y + u0.z*w0.z + u0.w*w0.w
                  + u1.x*w1.x + u1.y*w1.y + u1.z*w1.z + u1.w*w1.w;
        #pragma unroll
        for (int off = 32; off; off >>= 1) acc += __shfl_down(acc, off);
        if (lane == 0) q[b*HD + h] = acc + bq[h];
        return;
    }
    {   // scores init from user_emb: s(b) = SCL * sum_h (u.Wq[h]+bq[h])*bk[h]
        __shared__ float us[HD];
        __shared__ float sp[4];
        const int b = blk - PB_CONV_I - PB_CONV_W - PB_Q;
        us[tid]       = u[b*HD + tid];
        us[tid + 256] = u[b*HD + tid + 256];
        __syncthreads();
        float contrib = 0.f;
        #pragma unroll
        for (int hb = 0; hb < 2; hb++) {
            const int h = tid + hb*256;
            const float* wr = &Wq[(size_t)h*HD];
            float acc = 0.f;
            for (int j = 0; j < HD; j += 4) {
                float4 w4 = *(const float4*)&wr[j];
                float4 u4 = *(const float4*)&us[j];
                acc += u4.x*w4.x + u4.y*w4.y + u4.z*w4.z + u4.w*w4.w;
            }
            contrib += (acc + bq[h]) * bk[h];
        }
        #pragma unroll
        for (int off = 32; off; off >>= 1) contrib += __shfl_down(contrib, off);
        if ((tid & 63) == 0) sp[tid >> 6] = contrib;
        __syncthreads();
        const float s = (sp[0] + sp[1] + sp[2] + sp[3]) * SCL;
        float4 o = {s, s, s, s};
        *(float4*)&scores[b*LL + tid*4] = o;
    }
}

// ------- fused KV GEMM: k-half -> score partials (atomic), v-half -> v_bf ----
// A: MT x 512 bf16. Wkv: 1024 x 512 bf16 (k rows 0-511, v rows 512-1023).
// grid (8, 128): consecutive dispatch IDs share the A row-panel (L3 locality).
__global__ __launch_bounds__(256) void gemm_kv(
    const unsigned short* __restrict__ A, const unsigned short* __restrict__ W,
    const float* __restrict__ q, const float* __restrict__ bv,
    float* __restrict__ scores, unsigned short* __restrict__ v_bf)
{
    __shared__ unsigned short As[128 * 32];
    __shared__ unsigned short Bs[128 * 32];

    const int tid  = threadIdx.x;
    const int wave = tid >> 6, lane = tid & 63;
    const int wm = (wave >> 1) * 64;
    const int wn = (wave & 1)  * 64;
    const int row0 = blockIdx.y * 128;
    const int col0 = blockIdx.x * 128;        // <512 = k half

    const int lrr = lane >> 2;
    const int cc  = lane & 3;
    int st_row[2], st_gchunk[2];
    #pragma unroll
    for (int t = 0; t < 2; t++) {
        const int m = wave*32 + t*16 + lrr;
        st_row[t]    = m;
        st_gchunk[t] = cc ^ ((m >> 1) & 3);
    }

    const int fr   = lane & 15;
    const int quad = lane >> 4;

    f32x4 acc[4][4];
    #pragma unroll
    for (int i = 0; i < 4; i++)
        #pragma unroll
        for (int j = 0; j < 4; j++)
            acc[i][j] = (f32x4){0.f, 0.f, 0.f, 0.f};

    int a_off[4], b_off[4];
    #pragma unroll
    for (int i = 0; i < 4; i++) {
        const int m = wm + i*16 + fr;
        a_off[i] = m*32 + ((quad ^ ((m >> 1) & 3)) << 3);
        const int n = wn + i*16 + fr;
        b_off[i] = n*32 + ((quad ^ ((n >> 1) & 3)) << 3);
    }

    for (int k0 = 0; k0 < HD; k0 += 32) {
        #pragma unroll
        for (int t = 0; t < 2; t++) {
            const int m = st_row[t];
            const unsigned short* ga = &A[(size_t)(row0 + m)*HD + k0 + st_gchunk[t]*8];
            __builtin_amdgcn_global_load_lds(
                (const __attribute__((address_space(1))) void*)ga,
                (__attribute__((address_space(3))) void*)&As[(wave*32 + t*16)*32],
                16, 0, 0);
            const unsigned short* gw = &W[(size_t)(col0 + m)*HD + k0 + st_gchunk[t]*8];
            __builtin_amdgcn_global_load_lds(
                (const __attribute__((address_space(1))) void*)gw,
                (__attribute__((address_space(3))) void*)&Bs[(wave*32 + t*16)*32],
                16, 0, 0);
        }
        __syncthreads();

        bf16x8 af[4], bfr[4];
        #pragma unroll
        for (int i = 0; i < 4; i++) {
            af[i]  = *(const bf16x8*)&As[a_off[i]];
            bfr[i] = *(const bf16x8*)&Bs[b_off[i]];
        }
        #pragma unroll
        for (int i = 0; i < 4; i++)
            #pragma unroll
            for (int j = 0; j < 4; j++)
                acc[i][j] = __builtin_amdgcn_mfma_f32_16x16x32_bf16(
                    af[i], bfr[j], acc[i][j], 0, 0, 0);
        __syncthreads();
    }

    if (col0 < HD) {
        const int b = row0 >> 10;
        float qv[4];
        #pragma unroll
        for (int j = 0; j < 4; j++)
            qv[j] = q[b*HD + col0 + wn + j*16 + fr];
        #pragma unroll
        for (int i = 0; i < 4; i++) {
            #pragma unroll
            for (int r = 0; r < 4; r++) {
                float p = acc[i][0][r]*qv[0] + acc[i][1][r]*qv[1]
                        + acc[i][2][r]*qv[2] + acc[i][3][r]*qv[3];
                #pragma unroll
                for (int off = 1; off < 16; off <<= 1) p += __shfl_xor(p, off);
                if (fr == 0)
                    atomicAdd(&scores[row0 + wm + i*16 + quad*4 + r], p * SCL);
            }
        }
    } else {
        #pragma unroll
        for (int j = 0; j < 4; j++) {
            const int col = col0 - HD + wn + j*16 + fr;
            const float bb = bv[col];
            #pragma unroll
            for (int i = 0; i < 4; i++) {
                #pragma unroll
                for (int r = 0; r < 4; r++) {
                    const int row = row0 + wm + i*16 + quad*4 + r;
                    v_bf[(size_t)row*HD + col] = f2b(acc[i][j][r] + bb);
                }
            }
        }
    }
}

// ===== fused: attn (gather+softmax+PV) -> LDS A -> dense GEMM -> +res -> LN ==
// Block: 32 rows x full 512 cols. Phase 1: 4 waves x 8 rows attn into LDS.
// Phase 2: K-loop, A resident in LDS (stride 520 breaks bank period), W staged.
constexpr int ASTR = HD + 8;   // 520 elems, 1040 B row stride

__global__ __launch_bounds__(256) void attn_dense_ln(
    const float* __restrict__ scores, const int* __restrict__ index,
    const float* __restrict__ mask, const unsigned short* __restrict__ v,
    const unsigned short* __restrict__ W,    // Wd_bf, 512 x 512
    const float* __restrict__ bd, const unsigned short* __restrict__ res,
    const float* __restrict__ ln_g, const float* __restrict__ ln_b,
    float* __restrict__ out)
{
    __shared__ unsigned short As2[32 * ASTR]; // 33.3 KB, attn rows resident
    __shared__ unsigned short Bs[512 * 32];   // 32 KB
    __shared__ float g_s[HD], lb_s[HD];       // 4 KB
    __shared__ float rsum[4][32], rsq[4][32]; // 1 KB

    const int tid  = threadIdx.x;
    const int wave = tid >> 6, lane = tid & 63;
    const int row0 = blockIdx.x * 32;

    {   // stage gamma/beta
        const int i = tid * 2;
        *(float2*)&g_s[i]  = *(const float2*)&ln_g[i];
        *(float2*)&lb_s[i] = *(const float2*)&ln_b[i];
    }

    // ---- Phase 1: attention for rows [row0+wave*8, row0+wave*8+8) ----
    const int t31 = lane & 31;
    #pragma unroll
    for (int rr = 0; rr < 8; rr++) {
        const int lrow = wave*8 + rr;
        const int m = row0 + lrow;
        const int b = m >> 10, l = m & 1023;

        const int idx = index[l*KNBR + t31];
        const float s = scores[b*LL + idx] + mask[(size_t)m*KNBR + t31];
        float mx = s;
        #pragma unroll
        for (int off = 16; off; off >>= 1) mx = fmaxf(mx, __shfl_xor(mx, off));
        const float e = __expf(s - mx);
        float sum = e;
        #pragma unroll
        for (int off = 16; off; off >>= 1) sum += __shfl_xor(sum, off);
        const float w = e / sum;

        const unsigned short* vbase = v + (size_t)(b << 10) * HD + lane*8;
        float a[8] = {};
        #pragma unroll 8
        for (int t2 = 0; t2 < KNBR; t2++) {
            const int   it = __shfl(idx, t2);
            const float wt = __shfl(w,   t2);
            const uint4 pv = *(const uint4*)(vbase + (size_t)it*HD);
            a[0] += wt * b2f_lo(pv.x); a[1] += wt * b2f_hi(pv.x);
            a[2] += wt * b2f_lo(pv.y); a[3] += wt * b2f_hi(pv.y);
            a[4] += wt * b2f_lo(pv.z); a[5] += wt * b2f_hi(pv.z);
            a[6] += wt * b2f_lo(pv.w); a[7] += wt * b2f_hi(pv.w);
        }
        uint4 o;
        o.x = (unsigned int)f2b(a[0]) | ((unsigned int)f2b(a[1]) << 16);
        o.y = (unsigned int)f2b(a[2]) | ((unsigned int)f2b(a[3]) << 16);
        o.z = (unsigned int)f2b(a[4]) | ((unsigned int)f2b(a[5]) << 16);
        o.w = (unsigned int)f2b(a[6]) | ((unsigned int)f2b(a[7]) << 16);
        *(uint4*)&As2[lrow*ASTR + lane*8] = o;
    }
    __syncthreads();

    // ---- Phase 2: dense GEMM, A in LDS, W staged per k-chunk ----
    const int lrr  = lane >> 2;
    const int cc   = lane & 3;
    const int fr   = lane & 15;
    const int quad = lane >> 4;

    f32x4 acc[2][8];
    #pragma unroll
    for (int i = 0; i < 2; i++)
        #pragma unroll
        for (int j = 0; j < 8; j++)
            acc[i][j] = (f32x4){0.f, 0.f, 0.f, 0.f};

    int b_off[8];
    #pragma unroll
    for (int j = 0; j < 8; j++) {
        const int n = wave*128 + j*16 + fr;
        b_off[j] = n*32 + ((quad ^ ((n >> 1) & 3)) << 3);
    }
    int a_base[2];
    #pragma unroll
    for (int i = 0; i < 2; i++)
        a_base[i] = (i*16 + fr)*ASTR + quad*8;

    for (int k0 = 0; k0 < HD; k0 += 32) {
        #pragma unroll
        for (int t = 0; t < 8; t++) {
            const int n = wave*128 + t*16 + lrr;
            const int gch = cc ^ ((n >> 1) & 3);
            const unsigned short* gw = &W[(size_t)n*HD + k0 + gch*8];
            __builtin_amdgcn_global_load_lds(
                (const __attribute__((address_space(1))) void*)gw,
                (__attribute__((address_space(3))) void*)&Bs[(wave*128 + t*16)*32],
                16, 0, 0);
        }
        __syncthreads();

        bf16x8 af[2], bfr[8];
        #pragma unroll
        for (int i = 0; i < 2; i++) af[i] = *(const bf16x8*)&As2[a_base[i] + k0];
        #pragma unroll
        for (int j = 0; j < 8; j++) bfr[j] = *(const bf16x8*)&Bs[b_off[j]];
        #pragma unroll
        for (int i = 0; i < 2; i++)
            #pragma unroll
            for (int j = 0; j < 8; j++)
                acc[i][j] = __builtin_amdgcn_mfma_f32_16x16x32_bf16(
                    af[i], bfr[j], acc[i][j], 0, 0, 0);
        __syncthreads();
    }

    // ---- Epilogue: + bd + residual, row stats, LN, fp32 store ----
    float bdv[8];
    #pragma unroll
    for (int j = 0; j < 8; j++) bdv[j] = bd[wave*128 + j*16 + fr];

    #pragma unroll
    for (int i = 0; i < 2; i++) {
        #pragma unroll
        for (int r = 0; r < 4; r++) {
            const int lrow = i*16 + quad*4 + r;
            const size_t gr = (size_t)(row0 + lrow) * HD;
            float a1 = 0.f, a2 = 0.f;
            #pragma unroll
            for (int j = 0; j < 8; j++) {
                const int col = wave*128 + j*16 + fr;
                float val = acc[i][j][r] + bdv[j] + b2f(res[gr + col]);
                acc[i][j][r] = val;
                a1 += val; a2 += val*val;
            }
            #pragma unroll
            for (int off = 1; off < 16; off <<= 1) {
                a1 += __shfl_xor(a1, off);
                a2 += __shfl_xor(a2, off);
            }
            if (fr == 0) { rsum[wave][lrow] = a1; rsq[wave][lrow] = a2; }
        }
    }
    __syncthreads();

    #pragma unroll
    for (int i = 0; i < 2; i++) {
        #pragma unroll
        for (int r = 0; r < 4; r++) {
            const int lrow = i*16 + quad*4 + r;
            const float tot  = rsum[0][lrow] + rsum[1][lrow] + rsum[2][lrow] + rsum[3][lrow];
            const float tot2 = rsq[0][lrow]  + rsq[1][lrow]  + rsq[2][lrow]  + rsq[3][lrow];
            const float mu  = tot * (1.f/HD);
            const float var = tot2 * (1.f/HD) - mu*mu;
            const float inv = rsqrtf(var + 1e-12f);
            const size_t gr = (size_t)(row0 + lrow) * HD;
            #pragma unroll
            for (int j = 0; j < 8; j++) {
                const int col = wave*128 + j*16 + fr;
                out[gr + col] = (acc[i][j][r] - mu)*inv*g_s[col] + lb_s[col];
            }
        }
    }
}

extern "C" void kernel_launch(void* const* d_in, const int* in_sizes, int n_in,
                              void* d_out, int out_size, void* d_ws, size_t ws_size,
                              hipStream_t stream) {
    const float* user_emb = (const float*)d_in[0];
    const float* item_emb = (const float*)d_in[1];
    const float* mask     = (const float*)d_in[2];
    const int*   index    = (const int*)  d_in[3];
    const float* Wq = (const float*)d_in[4];  const float* bq = (const float*)d_in[5];
    const float* Wk = (const float*)d_in[6];  const float* bk = (const float*)d_in[7];
    const float* Wv = (const float*)d_in[8];  const float* bv = (const float*)d_in[9];
    const float* Wd = (const float*)d_in[10]; const float* bd = (const float*)d_in[11];
    const float* ln_g = (const float*)d_in[12];
    const float* ln_b = (const float*)d_in[13];

    float* out = (float*)d_out;

    char* p = (char*)d_ws;
    unsigned short* item_bf = (unsigned short*)p; p += (size_t)MT*HD*2;     // 16.8 MB
    unsigned short* v_bf    = (unsigned short*)p; p += (size_t)MT*HD*2;     // 16.8 MB
    unsigned short* Wkv_bf  = (unsigned short*)p; p += (size_t)2*HD*HD*2;   // 1 MB
    unsigned short* Wd_bf   = (unsigned short*)p; p += (size_t)HD*HD*2;     // 0.5 MB
    float* q      = (float*)p; p += 16*HD*4;
    float* scores = (float*)p; p += MT*4;

    // L1: everything independent (convs, q-proj, scores init)
    prep<<<PB_CONV_I + PB_CONV_W + PB_Q + PB_SINIT, 256, 0, stream>>>(
        item_emb, Wk, Wv, Wd, user_emb, Wq, bq, bk,
        item_bf, Wkv_bf, Wd_bf, q, scores);

    // L2: fused K+V GEMM; k half -> scores (atomic), v half -> v_bf
    gemm_kv<<<dim3(8, 128), 256, 0, stream>>>(item_bf, Wkv_bf, q, bv,
                                              scores, v_bf);

    // L3: attn + dense + residual + LN -> fp32 out
    attn_dense_ln<<<MT/32, 256, 0, stream>>>(scores, index, mask, v_bf,
                                             Wd_bf, bd, item_bf,
                                             ln_g, ln_b, out);
}

// Round 6
// 239.654 us; speedup vs baseline: 1.0585x; 1.0585x over previous
//
#include <hip/hip_runtime.h>
#include <math.h>

constexpr int HD   = 512;    // hidden
constexpr int LL   = 1024;   // SES*SEQ
constexpr int MT   = 16384;  // B*L rows
constexpr int KNBR = 32;     // K neighbors
constexpr float SCL = 0.04419417382415922f;  // 1/sqrt(512)

typedef __attribute__((ext_vector_type(8))) short  bf16x8;  // 8 bf16 = 4 VGPRs
typedef __attribute__((ext_vector_type(4))) float  f32x4;

__device__ inline float b2f(unsigned short u) {
    union { unsigned int i; float f; } v; v.i = (unsigned int)u << 16; return v.f;
}
__device__ inline float b2f_lo(unsigned int u) {
    union { unsigned int i; float f; } v; v.i = u << 16; return v.f;
}
__device__ inline float b2f_hi(unsigned int u) {
    union { unsigned int i; float f; } v; v.i = u & 0xffff0000u; return v.f;
}
__device__ inline unsigned short f2b(float x) {
    union { float f; unsigned int u; } v; v.f = x;
    unsigned int r = v.u + 0x7fff + ((v.u >> 16) & 1);
    return (unsigned short)(r >> 16);
}

// ================= prep: convs + per-batch (r, s0), one launch =============
// blocks [0,8192):      item fp32->bf16 (1024 elems/block)
// blocks [8192,8704):   Wv,Wd fp32->bf16
// blocks [8704,8720):   per-batch: q[b]=Wq u+bq; r[b]=SCL*Wk^T q; s0=SCL*q.bk
constexpr int PB_CONV_I = 8192;
constexpr int PB_CONV_W = 512;
constexpr int PB_QR     = 16;

__global__ __launch_bounds__(256) void prep(
    const float* __restrict__ item, const float* __restrict__ Wv,
    const float* __restrict__ Wd, const float* __restrict__ u,
    const float* __restrict__ Wq, const float* __restrict__ bq,
    const float* __restrict__ Wk, const float* __restrict__ bk,
    unsigned short* __restrict__ item_bf, unsigned short* __restrict__ Wv_bf,
    unsigned short* __restrict__ Wd_bf, float* __restrict__ rbuf,
    float* __restrict__ s0buf)
{
    const int blk = blockIdx.x, tid = threadIdx.x;

    if (blk < PB_CONV_I) {
        const int i = blk * 1024 + tid * 4;
        float4 v = *(const float4*)&item[i];
        ushort4 o;
        o.x = f2b(v.x); o.y = f2b(v.y); o.z = f2b(v.z); o.w = f2b(v.w);
        *(ushort4*)&item_bf[i] = o;
        return;
    }
    if (blk < PB_CONV_I + PB_CONV_W) {
        const int n = HD*HD;
        const int i = (blk - PB_CONV_I) * 1024 + tid * 4;
        const float* s; unsigned short* d; int off;
        if (i < n) { s = Wv; d = Wv_bf; off = i; }
        else       { s = Wd; d = Wd_bf; off = i - n; }
        float4 v = *(const float4*)&s[off];
        ushort4 o;
        o.x = f2b(v.x); o.y = f2b(v.y); o.z = f2b(v.z); o.w = f2b(v.w);
        *(ushort4*)&d[off] = o;
        return;
    }
    {   // per-batch q, r = SCL*Wk^T q, s0 = SCL*(q.bk)
        __shared__ float us[HD];
        __shared__ float qs[HD];
        __shared__ float sp[4];
        const int b = blk - PB_CONV_I - PB_CONV_W;
        us[tid]       = u[b*HD + tid];
        us[tid + 256] = u[b*HD + tid + 256];
        __syncthreads();
        // q[h] for h = tid, tid+256
        #pragma unroll
        for (int hb = 0; hb < 2; hb++) {
            const int h = tid + hb*256;
            const float* wr = &Wq[(size_t)h*HD];
            float acc = 0.f;
            for (int j = 0; j < HD; j += 4) {
                float4 w4 = *(const float4*)&wr[j];
                float4 u4 = *(const float4*)&us[j];
                acc += u4.x*w4.x + u4.y*w4.y + u4.z*w4.z + u4.w*w4.w;
            }
            qs[h] = acc + bq[h];
        }
        __syncthreads();
        // r[c] for c = tid*2, tid*2+1 : sum_h qs[h]*Wk[h][c]
        float r0 = 0.f, r1 = 0.f;
        const int c0 = tid * 2;
        #pragma unroll 8
        for (int h = 0; h < HD; h++) {
            const float2 w2 = *(const float2*)&Wk[(size_t)h*HD + c0];
            const float qh = qs[h];
            r0 += qh * w2.x; r1 += qh * w2.y;
        }
        rbuf[b*HD + c0]     = r0 * SCL;
        rbuf[b*HD + c0 + 1] = r1 * SCL;
        // s0 = SCL * dot(qs, bk)
        float p = qs[tid]*bk[tid] + qs[tid+256]*bk[tid+256];
        #pragma unroll
        for (int off = 32; off; off >>= 1) p += __shfl_down(p, off);
        if ((tid & 63) == 0) sp[tid >> 6] = p;
        __syncthreads();
        if (tid == 0) s0buf[b] = (sp[0] + sp[1] + sp[2] + sp[3]) * SCL;
    }
}

// ------- scores[m] = r[b] . item_bf[m] + s0[b], one wave per row -------
__global__ __launch_bounds__(256) void gp_scores(
    const float* __restrict__ rbuf, const float* __restrict__ s0buf,
    const unsigned short* __restrict__ item_bf, float* __restrict__ scores)
{
    const int m = blockIdx.x * 4 + (threadIdx.x >> 6);
    const int lane = threadIdx.x & 63;
    const int b = m >> 10;
    const unsigned short* ir = &item_bf[(size_t)m*HD + lane*8];
    const uint4 iv = *(const uint4*)ir;
    const float* rr = &rbuf[b*HD + lane*8];
    const float4 r0 = *(const float4*)rr;
    const float4 r1 = *(const float4*)(rr + 4);
    float acc = r0.x*b2f_lo(iv.x) + r0.y*b2f_hi(iv.x)
              + r0.z*b2f_lo(iv.y) + r0.w*b2f_hi(iv.y)
              + r1.x*b2f_lo(iv.z) + r1.y*b2f_hi(iv.z)
              + r1.z*b2f_lo(iv.w) + r1.w*b2f_hi(iv.w);
    #pragma unroll
    for (int off = 32; off; off >>= 1) acc += __shfl_down(acc, off);
    if (lane == 0) scores[m] = acc + s0buf[b];
}

// ------- V GEMM: v = item @ Wv^T + bv -> bf16 -------
// A: MT x 512 bf16. Wv_bf: 512 x 512 bf16. 128x128 tile, BK=32.
__global__ __launch_bounds__(256) void gemm_v(
    const unsigned short* __restrict__ A, const unsigned short* __restrict__ W,
    const float* __restrict__ bv, unsigned short* __restrict__ v_bf)
{
    __shared__ unsigned short As[128 * 32];
    __shared__ unsigned short Bs[128 * 32];

    const int tid  = threadIdx.x;
    const int wave = tid >> 6, lane = tid & 63;
    const int wm = (wave >> 1) * 64;
    const int wn = (wave & 1)  * 64;
    const int row0 = blockIdx.y * 128;
    const int col0 = blockIdx.x * 128;

    const int lrr = lane >> 2;
    const int cc  = lane & 3;
    int st_row[2], st_gchunk[2];
    #pragma unroll
    for (int t = 0; t < 2; t++) {
        const int m = wave*32 + t*16 + lrr;
        st_row[t]    = m;
        st_gchunk[t] = cc ^ ((m >> 1) & 3);
    }

    const int fr   = lane & 15;
    const int quad = lane >> 4;

    f32x4 acc[4][4];
    #pragma unroll
    for (int i = 0; i < 4; i++)
        #pragma unroll
        for (int j = 0; j < 4; j++)
            acc[i][j] = (f32x4){0.f, 0.f, 0.f, 0.f};

    int a_off[4], b_off[4];
    #pragma unroll
    for (int i = 0; i < 4; i++) {
        const int m = wm + i*16 + fr;
        a_off[i] = m*32 + ((quad ^ ((m >> 1) & 3)) << 3);
        const int n = wn + i*16 + fr;
        b_off[i] = n*32 + ((quad ^ ((n >> 1) & 3)) << 3);
    }

    for (int k0 = 0; k0 < HD; k0 += 32) {
        #pragma unroll
        for (int t = 0; t < 2; t++) {
            const int m = st_row[t];
            const unsigned short* ga = &A[(size_t)(row0 + m)*HD + k0 + st_gchunk[t]*8];
            __builtin_amdgcn_global_load_lds(
                (const __attribute__((address_space(1))) void*)ga,
                (__attribute__((address_space(3))) void*)&As[(wave*32 + t*16)*32],
                16, 0, 0);
            const unsigned short* gw = &W[(size_t)(col0 + m)*HD + k0 + st_gchunk[t]*8];
            __builtin_amdgcn_global_load_lds(
                (const __attribute__((address_space(1))) void*)gw,
                (__attribute__((address_space(3))) void*)&Bs[(wave*32 + t*16)*32],
                16, 0, 0);
        }
        __syncthreads();

        bf16x8 af[4], bfr[4];
        #pragma unroll
        for (int i = 0; i < 4; i++) {
            af[i]  = *(const bf16x8*)&As[a_off[i]];
            bfr[i] = *(const bf16x8*)&Bs[b_off[i]];
        }
        #pragma unroll
        for (int i = 0; i < 4; i++)
            #pragma unroll
            for (int j = 0; j < 4; j++)
                acc[i][j] = __builtin_amdgcn_mfma_f32_16x16x32_bf16(
                    af[i], bfr[j], acc[i][j], 0, 0, 0);
        __syncthreads();
    }

    #pragma unroll
    for (int j = 0; j < 4; j++) {
        const int col = col0 + wn + j*16 + fr;
        const float bb = bv[col];
        #pragma unroll
        for (int i = 0; i < 4; i++) {
            #pragma unroll
            for (int r = 0; r < 4; r++) {
                const int row = row0 + wm + i*16 + quad*4 + r;
                v_bf[(size_t)row*HD + col] = f2b(acc[i][j][r] + bb);
            }
        }
    }
}

// ----- gather + softmax + weighted sum of v: one wave per row -----
__global__ __launch_bounds__(256) void gp_attn(
    const float* __restrict__ scores, const int* __restrict__ index,
    const float* __restrict__ mask, const unsigned short* __restrict__ v,
    unsigned short* __restrict__ attn)
{
    const int m = blockIdx.x * 4 + (threadIdx.x >> 6);
    const int lane = threadIdx.x & 63;
    const int b = m >> 10, l = m & 1023;

    const int t = lane & 31;
    const int idx = index[l*KNBR + t];
    const float s = scores[b*LL + idx] + mask[(size_t)m*KNBR + t];

    float mx = s;
    #pragma unroll
    for (int off = 16; off; off >>= 1) mx = fmaxf(mx, __shfl_xor(mx, off));
    const float e = __expf(s - mx);
    float sum = e;
    #pragma unroll
    for (int off = 16; off; off >>= 1) sum += __shfl_xor(sum, off);
    const float w = e / sum;

    const unsigned short* vbase = v + (size_t)(b << 10) * HD + lane*8;
    float a[8] = {};
    #pragma unroll 8
    for (int t2 = 0; t2 < KNBR; t2++) {
        const int   it = __shfl(idx, t2);
        const float wt = __shfl(w,   t2);
        const uint4 pv = *(const uint4*)(vbase + (size_t)it*HD);
        a[0] += wt * b2f_lo(pv.x); a[1] += wt * b2f_hi(pv.x);
        a[2] += wt * b2f_lo(pv.y); a[3] += wt * b2f_hi(pv.y);
        a[4] += wt * b2f_lo(pv.z); a[5] += wt * b2f_hi(pv.z);
        a[6] += wt * b2f_lo(pv.w); a[7] += wt * b2f_hi(pv.w);
    }
    uint4 o;
    o.x = (unsigned int)f2b(a[0]) | ((unsigned int)f2b(a[1]) << 16);
    o.y = (unsigned int)f2b(a[2]) | ((unsigned int)f2b(a[3]) << 16);
    o.z = (unsigned int)f2b(a[4]) | ((unsigned int)f2b(a[5]) << 16);
    o.w = (unsigned int)f2b(a[6]) | ((unsigned int)f2b(a[7]) << 16);
    *(uint4*)&attn[(size_t)m*HD + lane*8] = o;
}

// ------- dense GEMM + residual + LayerNorm fused -------
// Block: 32 rows x full 512 cols. 4 waves, each a 128-col stripe (acc[2][8]).
__global__ __launch_bounds__(256) void dense_ln(
    const unsigned short* __restrict__ A,    // attn_bf, MT x 512
    const unsigned short* __restrict__ W,    // Wd_bf, 512 x 512
    const float* __restrict__ bd, const unsigned short* __restrict__ res,
    const float* __restrict__ ln_g, const float* __restrict__ ln_b,
    float* __restrict__ out)
{
    __shared__ unsigned short As[32 * 32];    // 2 KB
    __shared__ unsigned short Bs[512 * 32];   // 32 KB
    __shared__ float g_s[HD], lb_s[HD];       // 4 KB
    __shared__ float rsum[4][32], rsq[4][32]; // 1 KB

    const int tid  = threadIdx.x;
    const int wave = tid >> 6, lane = tid & 63;
    const int row0 = blockIdx.x * 32;

    {
        const int i = tid * 2;
        *(float2*)&g_s[i]  = *(const float2*)&ln_g[i];
        *(float2*)&lb_s[i] = *(const float2*)&ln_b[i];
    }

    const int lrr = lane >> 2;
    const int cc  = lane & 3;
    const int fr   = lane & 15;
    const int quad = lane >> 4;

    f32x4 acc[2][8];
    #pragma unroll
    for (int i = 0; i < 2; i++)
        #pragma unroll
        for (int j = 0; j < 8; j++)
            acc[i][j] = (f32x4){0.f, 0.f, 0.f, 0.f};

    int a_off[2], b_off[8];
    #pragma unroll
    for (int i = 0; i < 2; i++) {
        const int m = i*16 + fr;
        a_off[i] = m*32 + ((quad ^ ((m >> 1) & 3)) << 3);
    }
    #pragma unroll
    for (int j = 0; j < 8; j++) {
        const int n = wave*128 + j*16 + fr;
        b_off[j] = n*32 + ((quad ^ ((n >> 1) & 3)) << 3);
    }

    for (int k0 = 0; k0 < HD; k0 += 32) {
        #pragma unroll
        for (int t = 0; t < 8; t++) {
            const int n = wave*128 + t*16 + lrr;
            const int gch = cc ^ ((n >> 1) & 3);
            const unsigned short* gw = &W[(size_t)n*HD + k0 + gch*8];
            __builtin_amdgcn_global_load_lds(
                (const __attribute__((address_space(1))) void*)gw,
                (__attribute__((address_space(3))) void*)&Bs[(wave*128 + t*16)*32],
                16, 0, 0);
        }
        if (wave < 2) {
            const int m = wave*16 + lrr;
            const int gch = cc ^ ((m >> 1) & 3);
            const unsigned short* ga = &A[(size_t)(row0 + m)*HD + k0 + gch*8];
            __builtin_amdgcn_global_load_lds(
                (const __attribute__((address_space(1))) void*)ga,
                (__attribute__((address_space(3))) void*)&As[(wave*16)*32],
                16, 0, 0);
        }
        __syncthreads();

        bf16x8 af[2], bfr[8];
        #pragma unroll
        for (int i = 0; i < 2; i++) af[i] = *(const bf16x8*)&As[a_off[i]];
        #pragma unroll
        for (int j = 0; j < 8; j++) bfr[j] = *(const bf16x8*)&Bs[b_off[j]];
        #pragma unroll
        for (int i = 0; i < 2; i++)
            #pragma unroll
            for (int j = 0; j < 8; j++)
                acc[i][j] = __builtin_amdgcn_mfma_f32_16x16x32_bf16(
                    af[i], bfr[j], acc[i][j], 0, 0, 0);
        __syncthreads();
    }

    float bdv[8];
    #pragma unroll
    for (int j = 0; j < 8; j++) bdv[j] = bd[wave*128 + j*16 + fr];

    #pragma unroll
    for (int i = 0; i < 2; i++) {
        #pragma unroll
        for (int r = 0; r < 4; r++) {
            const int lrow = i*16 + quad*4 + r;
            const size_t gr = (size_t)(row0 + lrow) * HD;
            float a1 = 0.f, a2 = 0.f;
            #pragma unroll
            for (int j = 0; j < 8; j++) {
                const int col = wave*128 + j*16 + fr;
                float val = acc[i][j][r] + bdv[j] + b2f(res[gr + col]);
                acc[i][j][r] = val;
                a1 += val; a2 += val*val;
            }
            #pragma unroll
            for (int off = 1; off < 16; off <<= 1) {
                a1 += __shfl_xor(a1, off);
                a2 += __shfl_xor(a2, off);
            }
            if (fr == 0) { rsum[wave][lrow] = a1; rsq[wave][lrow] = a2; }
        }
    }
    __syncthreads();

    #pragma unroll
    for (int i = 0; i < 2; i++) {
        #pragma unroll
        for (int r = 0; r < 4; r++) {
            const int lrow = i*16 + quad*4 + r;
            const float tot  = rsum[0][lrow] + rsum[1][lrow] + rsum[2][lrow] + rsum[3][lrow];
            const float tot2 = rsq[0][lrow]  + rsq[1][lrow]  + rsq[2][lrow]  + rsq[3][lrow];
            const float mu  = tot * (1.f/HD);
            const float var = tot2 * (1.f/HD) - mu*mu;
            const float inv = rsqrtf(var + 1e-12f);
            const size_t gr = (size_t)(row0 + lrow) * HD;
            #pragma unroll
            for (int j = 0; j < 8; j++) {
                const int col = wave*128 + j*16 + fr;
                out[gr + col] = (acc[i][j][r] - mu)*inv*g_s[col] + lb_s[col];
            }
        }
    }
}

extern "C" void kernel_launch(void* const* d_in, const int* in_sizes, int n_in,
                              void* d_out, int out_size, void* d_ws, size_t ws_size,
                              hipStream_t stream) {
    const float* user_emb = (const float*)d_in[0];
    const float* item_emb = (const float*)d_in[1];
    const float* mask     = (const float*)d_in[2];
    const int*   index    = (const int*)  d_in[3];
    const float* Wq = (const float*)d_in[4];  const float* bq = (const float*)d_in[5];
    const float* Wk = (const float*)d_in[6];  const float* bk = (const float*)d_in[7];
    const float* Wv = (const float*)d_in[8];  const float* bv = (const float*)d_in[9];
    const float* Wd = (const float*)d_in[10]; const float* bd = (const float*)d_in[11];
    const float* ln_g = (const float*)d_in[12];
    const float* ln_b = (const float*)d_in[13];

    float* out = (float*)d_out;

    char* p = (char*)d_ws;
    unsigned short* item_bf = (unsigned short*)p; p += (size_t)MT*HD*2;     // 16.8 MB
    unsigned short* v_bf    = (unsigned short*)p; p += (size_t)MT*HD*2;     // 16.8 MB
    unsigned short* attn_bf = (unsigned short*)p; p += (size_t)MT*HD*2;     // 16.8 MB
    unsigned short* Wv_bf   = (unsigned short*)p; p += (size_t)HD*HD*2;     // 0.5 MB
    unsigned short* Wd_bf   = (unsigned short*)p; p += (size_t)HD*HD*2;     // 0.5 MB
    float* rbuf   = (float*)p; p += 16*HD*4;
    float* s0buf  = (float*)p; p += 16*4;
    float* scores = (float*)p; p += MT*4;

    // L1: convs + per-batch r/s0 (scores projected onto item-space)
    prep<<<PB_CONV_I + PB_CONV_W + PB_QR, 256, 0, stream>>>(
        item_emb, Wv, Wd, user_emb, Wq, bq, Wk, bk,
        item_bf, Wv_bf, Wd_bf, rbuf, s0buf);

    // L2: scores[m] = r[b].item_bf[m] + s0[b]
    gp_scores<<<MT/4, 256, 0, stream>>>(rbuf, s0buf, item_bf, scores);

    // L3: v = item @ Wv^T + bv (bf16)
    gemm_v<<<dim3(4, 128), 256, 0, stream>>>(item_bf, Wv_bf, bv, v_bf);

    // L4: gather + softmax + PV -> attn_bf
    gp_attn<<<MT/4, 256, 0, stream>>>(scores, index, mask, v_bf, attn_bf);

    // L5: dense + residual + LN -> fp32 out
    dense_ln<<<MT/32, 256, 0, stream>>>(attn_bf, Wd_bf, bd, item_bf,
                                        ln_g, ln_b, out);
}

// Round 7
// 191.104 us; speedup vs baseline: 1.3274x; 1.2541x over previous
//
#include <hip/hip_runtime.h>
#include <math.h>

constexpr int HD   = 512;    // hidden
constexpr int LL   = 1024;   // SES*SEQ
constexpr int MT   = 16384;  // B*L rows
constexpr int KNBR = 32;     // K neighbors
constexpr float SCL = 0.04419417382415922f;  // 1/sqrt(512)

typedef __attribute__((ext_vector_type(8))) short  bf16x8;  // 8 bf16 = 4 VGPRs
typedef __attribute__((ext_vector_type(4))) float  f32x4;

__device__ inline float b2f(unsigned short u) {
    union { unsigned int i; float f; } v; v.i = (unsigned int)u << 16; return v.f;
}
__device__ inline float b2f_lo(unsigned int u) {
    union { unsigned int i; float f; } v; v.i = u << 16; return v.f;
}
__device__ inline float b2f_hi(unsigned int u) {
    union { unsigned int i; float f; } v; v.i = u & 0xffff0000u; return v.f;
}
__device__ inline unsigned short f2b(float x) {
    union { float f; unsigned int u; } v; v.f = x;
    unsigned int r = v.u + 0x7fff + ((v.u >> 16) & 1);
    return (unsigned short)(r >> 16);
}

// ================= prep: convs + q-projection, one launch ==================
// blocks [0,8192):      item fp32->bf16 (1024 elems/block)
// blocks [8192,8704):   Wv,Wd fp32->bf16
// blocks [8704,10752):  q = user_emb @ Wq^T + bq, one wave per (b,h)
constexpr int PB_CONV_I = 8192;
constexpr int PB_CONV_W = 512;
constexpr int PB_Q      = 2048;

__global__ __launch_bounds__(256) void prep(
    const float* __restrict__ item, const float* __restrict__ Wv,
    const float* __restrict__ Wd, const float* __restrict__ u,
    const float* __restrict__ Wq, const float* __restrict__ bq,
    unsigned short* __restrict__ item_bf, unsigned short* __restrict__ Wv_bf,
    unsigned short* __restrict__ Wd_bf, float* __restrict__ q)
{
    const int blk = blockIdx.x, tid = threadIdx.x;

    if (blk < PB_CONV_I) {
        const int i = blk * 1024 + tid * 4;
        float4 v = *(const float4*)&item[i];
        ushort4 o;
        o.x = f2b(v.x); o.y = f2b(v.y); o.z = f2b(v.z); o.w = f2b(v.w);
        *(ushort4*)&item_bf[i] = o;
        return;
    }
    if (blk < PB_CONV_I + PB_CONV_W) {
        const int n = HD*HD;
        const int i = (blk - PB_CONV_I) * 1024 + tid * 4;
        const float* s; unsigned short* d; int off;
        if (i < n) { s = Wv; d = Wv_bf; off = i; }
        else       { s = Wd; d = Wd_bf; off = i - n; }
        float4 v = *(const float4*)&s[off];
        ushort4 o;
        o.x = f2b(v.x); o.y = f2b(v.y); o.z = f2b(v.z); o.w = f2b(v.w);
        *(ushort4*)&d[off] = o;
        return;
    }
    {   // q[b][h], one wave per (b,h)
        const int wid  = (blk - PB_CONV_I - PB_CONV_W) * 4 + (tid >> 6);
        const int lane = tid & 63;
        const int b = wid >> 9, h = wid & 511;
        const float* ur = &u[b*HD + lane*8];
        const float* wr = &Wq[(size_t)h*HD + lane*8];
        const float4 u0 = *(const float4*)ur, u1 = *(const float4*)(ur+4);
        const float4 w0 = *(const float4*)wr, w1 = *(const float4*)(wr+4);
        float acc = u0.x*w0.x + u0.y*w0.y + u0.z*w0.z + u0.w*w0.w
                  + u1.x*w1.x + u1.y*w1.y + u1.z*w1.z + u1.w*w1.w;
        #pragma unroll
        for (int off = 32; off; off >>= 1) acc += __shfl_down(acc, off);
        if (lane == 0) q[b*HD + h] = acc + bq[h];
    }
}

// ======= gemm_v_r: V GEMM + r matvec + s0, one launch =======
// blocks [0,512):    v = item @ Wv^T + bv -> bf16 (128x128 MFMA tiles)
// blocks [512,640):  r[b] = SCL * Wk^T q[b]   (16 b x 8 col-tiles of 64)
// blocks [640,656):  s0[b] = SCL * q[b].bk
__global__ __launch_bounds__(256) void gemm_v_r(
    const unsigned short* __restrict__ A, const unsigned short* __restrict__ W,
    const float* __restrict__ bv, const float* __restrict__ Wk,
    const float* __restrict__ bk, const float* __restrict__ q,
    unsigned short* __restrict__ v_bf, float* __restrict__ rbuf,
    float* __restrict__ s0buf)
{
    __shared__ unsigned short As[128 * 32];
    __shared__ unsigned short Bs[128 * 32];

    const int blk = blockIdx.x;
    const int tid = threadIdx.x;

    if (blk >= 512) {
        if (blk < 640) {
            // r[b][c0..c0+63] = SCL * sum_h q[b][h] * Wk[h][c]
            __shared__ float red[4][64];
            const int rblk = blk - 512;
            const int b = rblk >> 3, c0 = (rblk & 7) * 64;
            const int cl = tid & 63, hg = tid >> 6;
            const float* qb = &q[b*HD];
            const float* wb = &Wk[(size_t)hg*128*HD + c0 + cl];
            float acc = 0.f;
            #pragma unroll 8
            for (int h = 0; h < 128; h++)
                acc += qb[hg*128 + h] * wb[(size_t)h*HD];
            red[hg][cl] = acc;
            __syncthreads();
            if (tid < 64)
                rbuf[b*HD + c0 + tid] = SCL *
                    (red[0][tid] + red[1][tid] + red[2][tid] + red[3][tid]);
        } else {
            // s0[b] = SCL * q[b].bk
            __shared__ float sp[4];
            const int b = blk - 640;
            float p = q[b*HD + tid]*bk[tid] + q[b*HD + tid + 256]*bk[tid + 256];
            #pragma unroll
            for (int off = 32; off; off >>= 1) p += __shfl_down(p, off);
            if ((tid & 63) == 0) sp[tid >> 6] = p;
            __syncthreads();
            if (tid == 0) s0buf[b] = (sp[0] + sp[1] + sp[2] + sp[3]) * SCL;
        }
        return;
    }

    // ---- V GEMM tile ----
    const int wave = tid >> 6, lane = tid & 63;
    const int wm = (wave >> 1) * 64;
    const int wn = (wave & 1)  * 64;
    const int row0 = (blk >> 2) * 128;
    const int col0 = (blk & 3)  * 128;

    const int lrr = lane >> 2;
    const int cc  = lane & 3;
    int st_row[2], st_gchunk[2];
    #pragma unroll
    for (int t = 0; t < 2; t++) {
        const int m = wave*32 + t*16 + lrr;
        st_row[t]    = m;
        st_gchunk[t] = cc ^ ((m >> 1) & 3);
    }

    const int fr   = lane & 15;
    const int quad = lane >> 4;

    f32x4 acc[4][4];
    #pragma unroll
    for (int i = 0; i < 4; i++)
        #pragma unroll
        for (int j = 0; j < 4; j++)
            acc[i][j] = (f32x4){0.f, 0.f, 0.f, 0.f};

    int a_off[4], b_off[4];
    #pragma unroll
    for (int i = 0; i < 4; i++) {
        const int m = wm + i*16 + fr;
        a_off[i] = m*32 + ((quad ^ ((m >> 1) & 3)) << 3);
        const int n = wn + i*16 + fr;
        b_off[i] = n*32 + ((quad ^ ((n >> 1) & 3)) << 3);
    }

    for (int k0 = 0; k0 < HD; k0 += 32) {
        #pragma unroll
        for (int t = 0; t < 2; t++) {
            const int m = st_row[t];
            const unsigned short* ga = &A[(size_t)(row0 + m)*HD + k0 + st_gchunk[t]*8];
            __builtin_amdgcn_global_load_lds(
                (const __attribute__((address_space(1))) void*)ga,
                (__attribute__((address_space(3))) void*)&As[(wave*32 + t*16)*32],
                16, 0, 0);
            const unsigned short* gw = &W[(size_t)(col0 + m)*HD + k0 + st_gchunk[t]*8];
            __builtin_amdgcn_global_load_lds(
                (const __attribute__((address_space(1))) void*)gw,
                (__attribute__((address_space(3))) void*)&Bs[(wave*32 + t*16)*32],
                16, 0, 0);
        }
        __syncthreads();

        bf16x8 af[4], bfr[4];
        #pragma unroll
        for (int i = 0; i < 4; i++) {
            af[i]  = *(const bf16x8*)&As[a_off[i]];
            bfr[i] = *(const bf16x8*)&Bs[b_off[i]];
        }
        #pragma unroll
        for (int i = 0; i < 4; i++)
            #pragma unroll
            for (int j = 0; j < 4; j++)
                acc[i][j] = __builtin_amdgcn_mfma_f32_16x16x32_bf16(
                    af[i], bfr[j], acc[i][j], 0, 0, 0);
        __syncthreads();
    }

    #pragma unroll
    for (int j = 0; j < 4; j++) {
        const int col = col0 + wn + j*16 + fr;
        const float bb = bv[col];
        #pragma unroll
        for (int i = 0; i < 4; i++) {
            #pragma unroll
            for (int r = 0; r < 4; r++) {
                const int row = row0 + wm + i*16 + quad*4 + r;
                v_bf[(size_t)row*HD + col] = f2b(acc[i][j][r] + bb);
            }
        }
    }
}

// ------- scores[m] = r[b] . item_bf[m] + s0[b], one wave per row -------
__global__ __launch_bounds__(256) void gp_scores(
    const float* __restrict__ rbuf, const float* __restrict__ s0buf,
    const unsigned short* __restrict__ item_bf, float* __restrict__ scores)
{
    const int m = blockIdx.x * 4 + (threadIdx.x >> 6);
    const int lane = threadIdx.x & 63;
    const int b = m >> 10;
    const unsigned short* ir = &item_bf[(size_t)m*HD + lane*8];
    const uint4 iv = *(const uint4*)ir;
    const float* rr = &rbuf[b*HD + lane*8];
    const float4 r0 = *(const float4*)rr;
    const float4 r1 = *(const float4*)(rr + 4);
    float acc = r0.x*b2f_lo(iv.x) + r0.y*b2f_hi(iv.x)
              + r0.z*b2f_lo(iv.y) + r0.w*b2f_hi(iv.y)
              + r1.x*b2f_lo(iv.z) + r1.y*b2f_hi(iv.z)
              + r1.z*b2f_lo(iv.w) + r1.w*b2f_hi(iv.w);
    #pragma unroll
    for (int off = 32; off; off >>= 1) acc += __shfl_down(acc, off);
    if (lane == 0) scores[m] = acc + s0buf[b];
}

// ----- gather + softmax + weighted sum of v: one wave per row -----
__global__ __launch_bounds__(256) void gp_attn(
    const float* __restrict__ scores, const int* __restrict__ index,
    const float* __restrict__ mask, const unsigned short* __restrict__ v,
    unsigned short* __restrict__ attn)
{
    const int m = blockIdx.x * 4 + (threadIdx.x >> 6);
    const int lane = threadIdx.x & 63;
    const int b = m >> 10, l = m & 1023;

    const int t = lane & 31;
    const int idx = index[l*KNBR + t];
    const float s = scores[b*LL + idx] + mask[(size_t)m*KNBR + t];

    float mx = s;
    #pragma unroll
    for (int off = 16; off; off >>= 1) mx = fmaxf(mx, __shfl_xor(mx, off));
    const float e = __expf(s - mx);
    float sum = e;
    #pragma unroll
    for (int off = 16; off; off >>= 1) sum += __shfl_xor(sum, off);
    const float w = e / sum;

    const unsigned short* vbase = v + (size_t)(b << 10) * HD + lane*8;
    float a[8] = {};
    #pragma unroll 8
    for (int t2 = 0; t2 < KNBR; t2++) {
        const int   it = __shfl(idx, t2);
        const float wt = __shfl(w,   t2);
        const uint4 pv = *(const uint4*)(vbase + (size_t)it*HD);
        a[0] += wt * b2f_lo(pv.x); a[1] += wt * b2f_hi(pv.x);
        a[2] += wt * b2f_lo(pv.y); a[3] += wt * b2f_hi(pv.y);
        a[4] += wt * b2f_lo(pv.z); a[5] += wt * b2f_hi(pv.z);
        a[6] += wt * b2f_lo(pv.w); a[7] += wt * b2f_hi(pv.w);
    }
    uint4 o;
    o.x = (unsigned int)f2b(a[0]) | ((unsigned int)f2b(a[1]) << 16);
    o.y = (unsigned int)f2b(a[2]) | ((unsigned int)f2b(a[3]) << 16);
    o.z = (unsigned int)f2b(a[4]) | ((unsigned int)f2b(a[5]) << 16);
    o.w = (unsigned int)f2b(a[6]) | ((unsigned int)f2b(a[7]) << 16);
    *(uint4*)&attn[(size_t)m*HD + lane*8] = o;
}

// ------- dense GEMM + residual + LayerNorm fused -------
// Block: 32 rows x full 512 cols. 4 waves, each a 128-col stripe (acc[2][8]).
__global__ __launch_bounds__(256) void dense_ln(
    const unsigned short* __restrict__ A,    // attn_bf, MT x 512
    const unsigned short* __restrict__ W,    // Wd_bf, 512 x 512
    const float* __restrict__ bd, const unsigned short* __restrict__ res,
    const float* __restrict__ ln_g, const float* __restrict__ ln_b,
    float* __restrict__ out)
{
    __shared__ unsigned short As[32 * 32];    // 2 KB
    __shared__ unsigned short Bs[512 * 32];   // 32 KB
    __shared__ float g_s[HD], lb_s[HD];       // 4 KB
    __shared__ float rsum[4][32], rsq[4][32]; // 1 KB

    const int tid  = threadIdx.x;
    const int wave = tid >> 6, lane = tid & 63;
    const int row0 = blockIdx.x * 32;

    {
        const int i = tid * 2;
        *(float2*)&g_s[i]  = *(const float2*)&ln_g[i];
        *(float2*)&lb_s[i] = *(const float2*)&ln_b[i];
    }

    const int lrr = lane >> 2;
    const int cc  = lane & 3;
    const int fr   = lane & 15;
    const int quad = lane >> 4;

    f32x4 acc[2][8];
    #pragma unroll
    for (int i = 0; i < 2; i++)
        #pragma unroll
        for (int j = 0; j < 8; j++)
            acc[i][j] = (f32x4){0.f, 0.f, 0.f, 0.f};

    int a_off[2], b_off[8];
    #pragma unroll
    for (int i = 0; i < 2; i++) {
        const int m = i*16 + fr;
        a_off[i] = m*32 + ((quad ^ ((m >> 1) & 3)) << 3);
    }
    #pragma unroll
    for (int j = 0; j < 8; j++) {
        const int n = wave*128 + j*16 + fr;
        b_off[j] = n*32 + ((quad ^ ((n >> 1) & 3)) << 3);
    }

    for (int k0 = 0; k0 < HD; k0 += 32) {
        #pragma unroll
        for (int t = 0; t < 8; t++) {
            const int n = wave*128 + t*16 + lrr;
            const int gch = cc ^ ((n >> 1) & 3);
            const unsigned short* gw = &W[(size_t)n*HD + k0 + gch*8];
            __builtin_amdgcn_global_load_lds(
                (const __attribute__((address_space(1))) void*)gw,
                (__attribute__((address_space(3))) void*)&Bs[(wave*128 + t*16)*32],
                16, 0, 0);
        }
        if (wave < 2) {
            const int m = wave*16 + lrr;
            const int gch = cc ^ ((m >> 1) & 3);
            const unsigned short* ga = &A[(size_t)(row0 + m)*HD + k0 + gch*8];
            __builtin_amdgcn_global_load_lds(
                (const __attribute__((address_space(1))) void*)ga,
                (__attribute__((address_space(3))) void*)&As[(wave*16)*32],
                16, 0, 0);
        }
        __syncthreads();

        bf16x8 af[2], bfr[8];
        #pragma unroll
        for (int i = 0; i < 2; i++) af[i] = *(const bf16x8*)&As[a_off[i]];
        #pragma unroll
        for (int j = 0; j < 8; j++) bfr[j] = *(const bf16x8*)&Bs[b_off[j]];
        #pragma unroll
        for (int i = 0; i < 2; i++)
            #pragma unroll
            for (int j = 0; j < 8; j++)
                acc[i][j] = __builtin_amdgcn_mfma_f32_16x16x32_bf16(
                    af[i], bfr[j], acc[i][j], 0, 0, 0);
        __syncthreads();
    }

    float bdv[8];
    #pragma unroll
    for (int j = 0; j < 8; j++) bdv[j] = bd[wave*128 + j*16 + fr];

    #pragma unroll
    for (int i = 0; i < 2; i++) {
        #pragma unroll
        for (int r = 0; r < 4; r++) {
            const int lrow = i*16 + quad*4 + r;
            const size_t gr = (size_t)(row0 + lrow) * HD;
            float a1 = 0.f, a2 = 0.f;
            #pragma unroll
            for (int j = 0; j < 8; j++) {
                const int col = wave*128 + j*16 + fr;
                float val = acc[i][j][r] + bdv[j] + b2f(res[gr + col]);
                acc[i][j][r] = val;
                a1 += val; a2 += val*val;
            }
            #pragma unroll
            for (int off = 1; off < 16; off <<= 1) {
                a1 += __shfl_xor(a1, off);
                a2 += __shfl_xor(a2, off);
            }
            if (fr == 0) { rsum[wave][lrow] = a1; rsq[wave][lrow] = a2; }
        }
    }
    __syncthreads();

    #pragma unroll
    for (int i = 0; i < 2; i++) {
        #pragma unroll
        for (int r = 0; r < 4; r++) {
            const int lrow = i*16 + quad*4 + r;
            const float tot  = rsum[0][lrow] + rsum[1][lrow] + rsum[2][lrow] + rsum[3][lrow];
            const float tot2 = rsq[0][lrow]  + rsq[1][lrow]  + rsq[2][lrow]  + rsq[3][lrow];
            const float mu  = tot * (1.f/HD);
            const float var = tot2 * (1.f/HD) - mu*mu;
            const float inv = rsqrtf(var + 1e-12f);
            const size_t gr = (size_t)(row0 + lrow) * HD;
            #pragma unroll
            for (int j = 0; j < 8; j++) {
                const int col = wave*128 + j*16 + fr;
                out[gr + col] = (acc[i][j][r] - mu)*inv*g_s[col] + lb_s[col];
            }
        }
    }
}

extern "C" void kernel_launch(void* const* d_in, const int* in_sizes, int n_in,
                              void* d_out, int out_size, void* d_ws, size_t ws_size,
                              hipStream_t stream) {
    const float* user_emb = (const float*)d_in[0];
    const float* item_emb = (const float*)d_in[1];
    const float* mask     = (const float*)d_in[2];
    const int*   index    = (const int*)  d_in[3];
    const float* Wq = (const float*)d_in[4];  const float* bq = (const float*)d_in[5];
    const float* Wk = (const float*)d_in[6];  const float* bk = (const float*)d_in[7];
    const float* Wv = (const float*)d_in[8];  const float* bv = (const float*)d_in[9];
    const float* Wd = (const float*)d_in[10]; const float* bd = (const float*)d_in[11];
    const float* ln_g = (const float*)d_in[12];
    const float* ln_b = (const float*)d_in[13];

    float* out = (float*)d_out;

    char* p = (char*)d_ws;
    unsigned short* item_bf = (unsigned short*)p; p += (size_t)MT*HD*2;     // 16.8 MB
    unsigned short* v_bf    = (unsigned short*)p; p += (size_t)MT*HD*2;     // 16.8 MB
    unsigned short* attn_bf = (unsigned short*)p; p += (size_t)MT*HD*2;     // 16.8 MB
    unsigned short* Wv_bf   = (unsigned short*)p; p += (size_t)HD*HD*2;     // 0.5 MB
    unsigned short* Wd_bf   = (unsigned short*)p; p += (size_t)HD*HD*2;     // 0.5 MB
    float* q      = (float*)p; p += 16*HD*4;
    float* rbuf   = (float*)p; p += 16*HD*4;
    float* s0buf  = (float*)p; p += 16*4;
    float* scores = (float*)p; p += MT*4;

    // L1: convs + q projection (all parallel, no serial tail)
    prep<<<PB_CONV_I + PB_CONV_W + PB_Q, 256, 0, stream>>>(
        item_emb, Wv, Wd, user_emb, Wq, bq,
        item_bf, Wv_bf, Wd_bf, q);

    // L2: V GEMM + r matvec + s0 (all depend only on prep)
    gemm_v_r<<<656, 256, 0, stream>>>(item_bf, Wv_bf, bv, Wk, bk, q,
                                      v_bf, rbuf, s0buf);

    // L3: scores[m] = r[b].item_bf[m] + s0[b]
    gp_scores<<<MT/4, 256, 0, stream>>>(rbuf, s0buf, item_bf, scores);

    // L4: gather + softmax + PV -> attn_bf
    gp_attn<<<MT/4, 256, 0, stream>>>(scores, index, mask, v_bf, attn_bf);

    // L5: dense + residual + LN -> fp32 out
    dense_ln<<<MT/32, 256, 0, stream>>>(attn_bf, Wd_bf, bd, item_bf,
                                        ln_g, ln_b, out);
}